// Round 1
// 1139.678 us; speedup vs baseline: 1.0060x; 1.0060x over previous
//
#include <hip/hip_runtime.h>
#include <math.h>

#define N_ROWS 8192
#define A_ART  32
#define D_DIM  768
#define O_DIM  256
#define LN_EPS 1e-5f
#define R_TILE 16
#define P_STR  772   // pooled LDS leading dim: bank = (4r+d)%32 -> <=2-way (free)

typedef unsigned short u16;
typedef unsigned int   u32;

__device__ __forceinline__ float bf2f(u16 u) { return __uint_as_float(((u32)u) << 16); }
__device__ __forceinline__ u16 f2bf(float f) {
    u32 x = __float_as_uint(f);
    return (u16)((x + 0x7fffu + ((x >> 16) & 1u)) >> 16);  // RNE
}
__device__ __forceinline__ float ldf(const void* p, int i, bool bf) {
    return bf ? bf2f(((const u16*)p)[i]) : ((const float*)p)[i];
}

// ws layout (bytes): 256: projw_f32 [768*256] (bf16 input case only)
#define WS_PROJW 256

// ---------------- projw bf16->f32 conversion (bf16 case only) ----------------
// Per-block inline dtype detect (reads same 256 B of articles; L2 broadcast).
__global__ __launch_bounds__(256) void convw_kernel(const void* __restrict__ proj_w,
                                                    const u32* __restrict__ art_w,
                                                    float* __restrict__ projw_f) {
    __shared__ int sbf;
    const int t = threadIdx.x;
    if (t < 64) {
        u32 w = art_w[t];
        u32 low = w & 0xffffu;
        u32 e = (low >> 7) & 0xffu;
        bool sane = (e >= 100u && e <= 140u) || ((low & 0x7fffu) == 0u);
        unsigned long long m1 = __ballot(sane);
        if (t == 0) sbf = (__popcll(m1) >= 48) ? 1 : 0;
    }
    __syncthreads();
    if (!sbf) return;                       // f32 input: no conversion needed
    const int i = blockIdx.x * 256 + t;
    projw_f[i] = bf2f(((const u16*)proj_w)[i]);
}

// ---------------- fused: online-softmax pool (LDS) + proj + LN + GELU ----------------
#define ONLINE_STEP                                                          \
    {                                                                        \
        float s = 0.f;                                                       \
        _Pragma("unroll")                                                    \
        for (int k = 0; k < 12; ++k) s = fmaf(art[k], wfrag[k], s);          \
        _Pragma("unroll")                                                    \
        for (int off = 32; off; off >>= 1) s += __shfl_xor(s, off);          \
        s += bias;                                                           \
        float mn = fmaxf(m, s);                                              \
        float scale = __expf(m - mn);                                        \
        float p = __expf(s - mn);                                            \
        l = l * scale + p;                                                   \
        _Pragma("unroll")                                                    \
        for (int k = 0; k < 12; ++k) acc[k] = fmaf(p, art[k], acc[k] * scale); \
        m = mn;                                                              \
    }

__global__ __launch_bounds__(512, 4) void fused_kernel(
        const void* __restrict__ articles, const int* __restrict__ counts32,
        const void* __restrict__ attn_w, const void* __restrict__ attn_b,
        const void* __restrict__ proj_b, const void* __restrict__ ln_w,
        const void* __restrict__ ln_b, const void* __restrict__ no_news,
        const float* __restrict__ projw_f, const void* __restrict__ proj_w_raw,
        void* __restrict__ out) {
    __shared__ float lds_p[R_TILE * P_STR];   // 49.4 KB pooled tile
    __shared__ float lds_s[R_TILE * 16];
    __shared__ float lds_q[R_TILE * 16];
    __shared__ float lds_mu[R_TILE];
    __shared__ float lds_rs[R_TILE];
    __shared__ int   sflags[2];

    const int t    = threadIdx.x;
    const int wave = t >> 6, lane = t & 63;

    // inline dtype detection (wave 0), identical logic to old detect_kernel
    if (t < 64) {
        u32 w = ((const u32*)articles)[t];
        u32 low = w & 0xffffu;
        u32 e = (low >> 7) & 0xffu;
        bool sane = (e >= 100u && e <= 140u) || ((low & 0x7fffu) == 0u);
        unsigned long long m1 = __ballot(sane);
        bool hz = true;
        if (t < 32) hz = (counts32[2 * t + 1] == 0);
        unsigned long long m2 = __ballot(hz);
        if (t == 0) {
            sflags[0] = (__popcll(m1) >= 48) ? 1 : 0;
            sflags[1] = (m2 == ~0ull) ? 1 : 0;
        }
    }
    __syncthreads();
    const bool bf  = sflags[0] != 0;
    const bool c64 = sflags[1] != 0;

    // per-lane attn_w fragment: d = 4*(lane+64j)+k  (read raw, dtype-branched)
    float wfrag[12];
    if (bf) {
        const u16* aw = (const u16*)attn_w;
        #pragma unroll
        for (int j = 0; j < 3; ++j) {
            uint2 q = *(const uint2*)(aw + 4 * (lane + 64 * j));
            wfrag[4 * j + 0] = bf2f((u16)(q.x & 0xffffu));
            wfrag[4 * j + 1] = bf2f((u16)(q.x >> 16));
            wfrag[4 * j + 2] = bf2f((u16)(q.y & 0xffffu));
            wfrag[4 * j + 3] = bf2f((u16)(q.y >> 16));
        }
    } else {
        #pragma unroll
        for (int j = 0; j < 3; ++j) {
            float4 wv = *(const float4*)((const float*)attn_w + 4 * (lane + 64 * j));
            wfrag[4 * j + 0] = wv.x; wfrag[4 * j + 1] = wv.y;
            wfrag[4 * j + 2] = wv.z; wfrag[4 * j + 3] = wv.w;
        }
    }
    const float bias = ldf(attn_b, 0, bf);

    const int row0 = blockIdx.x * R_TILE;

    // ---- pool phase: each of 8 waves owns 2 rows; full-wave shfl-reduce dot;
    //      online softmax entirely per-wave (no cross-wave merge needed) ----
    for (int i = 0; i < 2; ++i) {
        const int r = wave * 2 + i;          // local row 0..15
        const int n = row0 + r;
        const int c = counts32[c64 ? 2 * n : n];

        float m = -1e30f, l = 0.f;
        float acc[12];
        #pragma unroll
        for (int k = 0; k < 12; ++k) acc[k] = 0.f;

        if (c > 0) {
            if (bf) {
                const u16* base = (const u16*)articles + (size_t)n * (A_ART * D_DIM);
                for (int a = 0; a < c; ++a) {
                    float art[12];
                    #pragma unroll
                    for (int j = 0; j < 3; ++j) {
                        uint2 q = *(const uint2*)(base + a * D_DIM + 4 * (lane + 64 * j));
                        art[4 * j + 0] = bf2f((u16)(q.x & 0xffffu));
                        art[4 * j + 1] = bf2f((u16)(q.x >> 16));
                        art[4 * j + 2] = bf2f((u16)(q.y & 0xffffu));
                        art[4 * j + 3] = bf2f((u16)(q.y >> 16));
                    }
                    ONLINE_STEP
                }
            } else {
                const float* base = (const float*)articles + (size_t)n * (A_ART * D_DIM);
                for (int a = 0; a < c; ++a) {
                    float art[12];
                    #pragma unroll
                    for (int j = 0; j < 3; ++j) {
                        float4 q = *(const float4*)(base + a * D_DIM + 4 * (lane + 64 * j));
                        art[4 * j + 0] = q.x; art[4 * j + 1] = q.y;
                        art[4 * j + 2] = q.z; art[4 * j + 3] = q.w;
                    }
                    ONLINE_STEP
                }
            }
            const float invL = __frcp_rn(l);
            #pragma unroll
            for (int k = 0; k < 12; ++k) acc[k] *= invL;
        }
        // normalized pooled row straight into LDS (c==0 -> zeros, select later)
        #pragma unroll
        for (int j = 0; j < 3; ++j)
            *((float4*)&lds_p[r * P_STR + 4 * (lane + 64 * j)]) =
                make_float4(acc[4 * j + 0], acc[4 * j + 1], acc[4 * j + 2], acc[4 * j + 3]);
    }
    __syncthreads();

    // ---- proj phase: 256 active threads, acc[16] per thread (dense FMA) ----
    const bool active = (t < 256);
    const int  tr = t & 15;
    const int  ob = (t >> 4) * 16;

    float acc[16];
    #pragma unroll
    for (int j = 0; j < 16; ++j) acc[j] = 0.f;

    if (active) {
        const float* W = bf ? projw_f : (const float*)proj_w_raw;
        for (int d = 0; d < D_DIM; ++d) {
            const float pv = lds_p[tr * P_STR + d];
            const float4* wrow = (const float4*)(W + d * O_DIM + ob);
            float4 wa = wrow[0], wb = wrow[1], wc = wrow[2], wd = wrow[3];
            acc[0]  = fmaf(pv, wa.x, acc[0]);  acc[1]  = fmaf(pv, wa.y, acc[1]);
            acc[2]  = fmaf(pv, wa.z, acc[2]);  acc[3]  = fmaf(pv, wa.w, acc[3]);
            acc[4]  = fmaf(pv, wb.x, acc[4]);  acc[5]  = fmaf(pv, wb.y, acc[5]);
            acc[6]  = fmaf(pv, wb.z, acc[6]);  acc[7]  = fmaf(pv, wb.w, acc[7]);
            acc[8]  = fmaf(pv, wc.x, acc[8]);  acc[9]  = fmaf(pv, wc.y, acc[9]);
            acc[10] = fmaf(pv, wc.z, acc[10]); acc[11] = fmaf(pv, wc.w, acc[11]);
            acc[12] = fmaf(pv, wd.x, acc[12]); acc[13] = fmaf(pv, wd.y, acc[13]);
            acc[14] = fmaf(pv, wd.z, acc[14]); acc[15] = fmaf(pv, wd.w, acc[15]);
        }
        float ps = 0.f, pq = 0.f;
        #pragma unroll
        for (int j = 0; j < 16; ++j) {
            acc[j] += ldf(proj_b, ob + j, bf);
            ps += acc[j];
            pq += acc[j] * acc[j];
        }
        lds_s[tr * 16 + (t >> 4)] = ps;
        lds_q[tr * 16 + (t >> 4)] = pq;
    }
    __syncthreads();

    if (t < 16) {
        float s = 0.f, qq = 0.f;
        #pragma unroll
        for (int g = 0; g < 16; ++g) { s += lds_s[t * 16 + g]; qq += lds_q[t * 16 + g]; }
        float mu  = s * (1.0f / O_DIM);
        float var = qq * (1.0f / O_DIM) - mu * mu;
        lds_mu[t] = mu;
        lds_rs[t] = rsqrtf(var + LN_EPS);
    }
    __syncthreads();

    if (active) {
        const float mu = lds_mu[tr];
        const float rs = lds_rs[tr];
        const int row = row0 + tr;
        const int cnt = counts32[c64 ? 2 * row : row];

        float vals[16];
        #pragma unroll
        for (int j = 0; j < 16; ++j) {
            const int o = ob + j;
            float x = (acc[j] - mu) * rs * ldf(ln_w, o, bf) + ldf(ln_b, o, bf);
            float g = 0.5f * x * (1.0f + erff(x * 0.70710678118654752f));
            vals[j] = (cnt > 0) ? g : ldf(no_news, o, bf);
        }

        if (bf) {
            u16 obuf[16];
            #pragma unroll
            for (int j = 0; j < 16; ++j) obuf[j] = f2bf(vals[j]);
            uint4* dst = (uint4*)((u16*)out + (size_t)row * O_DIM + ob);
            dst[0] = *((const uint4*)&obuf[0]);
            dst[1] = *((const uint4*)&obuf[8]);
        } else {
            float4* dst = (float4*)((float*)out + (size_t)row * O_DIM + ob);
            dst[0] = *((const float4*)&vals[0]);
            dst[1] = *((const float4*)&vals[4]);
            dst[2] = *((const float4*)&vals[8]);
            dst[3] = *((const float4*)&vals[12]);
        }
    }
}

extern "C" void kernel_launch(void* const* d_in, const int* in_sizes, int n_in,
                              void* d_out, int out_size, void* d_ws, size_t ws_size,
                              hipStream_t stream) {
    const void* articles = d_in[0];
    const int*  counts   = (const int*)d_in[1];
    float* projw_f = (float*)((char*)d_ws + WS_PROJW);

    convw_kernel<<<768, 256, 0, stream>>>(d_in[4], (const u32*)articles, projw_f);
    fused_kernel<<<N_ROWS / R_TILE, 512, 0, stream>>>(
        articles, counts, d_in[2], d_in[3], d_in[5], d_in[6], d_in[7], d_in[8],
        projw_f, d_in[4], d_out);
}